// Round 1
// baseline (69366.809 us; speedup 1.0000x reference)
//
#include <hip/hip_runtime.h>
#include <math.h>

#define NSMP 48

__device__ __forceinline__ float gelu_f(float x){
    return 0.5f*x*(1.0f+erff(x*0.70710678118654752f));
}

// fold one feature channel into sigma or the layer-1 accumulator
__device__ __forceinline__ void accum_feat(int krgb, int c, float f, float& sigma,
                                           float* hid, const float* s_wmat){
    if (c < 8){ sigma += f; }
    else {
        const float g = gelu_f(f);
        const float4* wr = (const float4*)(s_wmat + (krgb + c - 8)*64);
        #pragma unroll
        for (int j=0;j<16;j++){
            const float4 w = wr[j];
            hid[4*j+0] += g*w.x;
            hid[4*j+1] += g*w.y;
            hid[4*j+2] += g*w.z;
            hid[4*j+3] += g*w.w;
        }
    }
}

template<bool TR>
__global__ __launch_bounds__(256)
void render_kernel(const float* __restrict__ rays_o,
                   const float* __restrict__ rays_d,
                   const float* __restrict__ mats,
                   const float* __restrict__ vecs,
                   const float* __restrict__ g_wmat, const float* __restrict__ g_bmat,
                   const float* __restrict__ g_w1,  const float* __restrict__ g_b1,
                   const float* __restrict__ g_w2,  const float* __restrict__ g_b2,
                   float* __restrict__ out, int B, int R)
{
    __shared__ __align__(16) float s_wmat[72*64];
    __shared__ __align__(16) float s_w1[91*64];
    __shared__ float s_bmat[64];
    __shared__ float s_b1[64];
    __shared__ float s_w2[64*3];
    __shared__ float s_b2[3];

    const int tid = threadIdx.x;
    for (int i=tid;i<72*64;i+=256) s_wmat[i]=g_wmat[i];
    for (int i=tid;i<91*64;i+=256) s_w1[i]=g_w1[i];
    if (tid<64){ s_bmat[tid]=g_bmat[tid]; s_b1[tid]=g_b1[tid]; }
    if (tid<192) s_w2[tid]=g_w2[tid];
    if (tid<3)  s_b2[tid]=g_b2[tid];
    __syncthreads();

    const int lane = tid & 63;
    const int ray  = blockIdx.x*4 + (tid>>6);
    const int NR   = B*R;
    if (ray >= NR) return;
    const int b    = ray / R;

    const float ox=rays_o[ray*3+0], oy=rays_o[ray*3+1], oz=rays_o[ray*3+2];
    const float dx=rays_d[ray*3+0], dy=rays_d[ray*3+1], dz=rays_d[ray*3+2];

    const int s = lane;
    const bool active = (s < NSMP);
    const float mid = ((float)s + 0.5f) * 0.03125f;   // (FAR-NEAR)/NS = 1.5/48

    // xyz = (pts+0.8)*1.25-1 = 1.25*pts
    const float x0c = 1.25f*(ox + dx*mid);
    const float x1c = 1.25f*(oy + dy*mid);
    const float x2c = 1.25f*(oz + dz*mid);

    float hid[64];
    #pragma unroll
    for (int j=0;j<64;j++) hid[j] = s_bmat[j];
    float sigma = 0.0f;

    for (int i=0;i<3;i++){
        // MAT_MODE = {{0,1},{2,0},{1,2}}, VEC_MODE = {2,1,0}
        const float cx = (i==0)? x0c : (i==1)? x2c : x1c;
        const float cy = (i==0)? x1c : (i==1)? x0c : x2c;
        const float cv = (i==0)? x2c : (i==1)? x1c : x0c;

        const float px = (cx+1.0f)*23.5f;   // 0.5*(48-1)
        const float py = (cy+1.0f)*23.5f;
        const float fx0 = floorf(px), fy0 = floorf(py);
        const float wx = px-fx0, wy = py-fy0;
        const int ix0 = (int)fx0, iy0 = (int)fy0;

        int   toff[4];
        float tw[4];
        #pragma unroll
        for (int t=0;t<4;t++){
            const int xx = ix0 + (t&1);
            const int yy = iy0 + (t>>1);
            const bool inb = (xx>=0)&&(xx<48)&&(yy>=0)&&(yy<48);
            const int xcl = min(max(xx,0),47);
            const int ycl = min(max(yy,0),47);
            toff[t] = ycl*48+xcl;
            const float wxx = (t&1)? wx : 1.0f-wx;
            const float wyy = (t>>1)? wy : 1.0f-wy;
            tw[t] = inb ? wxx*wyy : 0.0f;
        }

        const float pv = (cv+1.0f)*23.5f;
        const float fp0 = floorf(pv);
        const float wv = pv-fp0;
        const int ip0 = (int)fp0;
        int voff[2]; float vw[2];
        #pragma unroll
        for (int t=0;t<2;t++){
            const int pp = ip0+t;
            const bool inb = (pp>=0)&&(pp<48);
            voff[t] = min(max(pp,0),47);
            vw[t] = inb ? ((t)? wv : 1.0f-wv) : 0.0f;
        }

        const int krgb = i*24;
        if (TR){
            // channel-last layout: [ib][pix][32] and [ib][r][32]
            const float* pb = mats + ((size_t)(i*B+b))*(2304u*32u);
            const float* vb = vecs + ((size_t)(i*B+b))*(48u*32u);
            const float4* t0 = (const float4*)(pb + toff[0]*32);
            const float4* t1 = (const float4*)(pb + toff[1]*32);
            const float4* t2 = (const float4*)(pb + toff[2]*32);
            const float4* t3 = (const float4*)(pb + toff[3]*32);
            const float4* v0 = (const float4*)(vb + voff[0]*32);
            const float4* v1 = (const float4*)(vb + voff[1]*32);
            for (int c4=0;c4<8;c4++){
                const float4 a0=t0[c4], a1=t1[c4], a2=t2[c4], a3=t3[c4];
                const float4 q0=v0[c4], q1=v1[c4];
                float f;
                f = (tw[0]*a0.x+tw[1]*a1.x+tw[2]*a2.x+tw[3]*a3.x)*(vw[0]*q0.x+vw[1]*q1.x);
                accum_feat(krgb, c4*4+0, f, sigma, hid, s_wmat);
                f = (tw[0]*a0.y+tw[1]*a1.y+tw[2]*a2.y+tw[3]*a3.y)*(vw[0]*q0.y+vw[1]*q1.y);
                accum_feat(krgb, c4*4+1, f, sigma, hid, s_wmat);
                f = (tw[0]*a0.z+tw[1]*a1.z+tw[2]*a2.z+tw[3]*a3.z)*(vw[0]*q0.z+vw[1]*q1.z);
                accum_feat(krgb, c4*4+2, f, sigma, hid, s_wmat);
                f = (tw[0]*a0.w+tw[1]*a1.w+tw[2]*a2.w+tw[3]*a3.w)*(vw[0]*q0.w+vw[1]*q1.w);
                accum_feat(krgb, c4*4+3, f, sigma, hid, s_wmat);
            }
        } else {
            // original layout: [ib][c][2304] and [ib][c][48]
            const float* pb = mats + ((size_t)(i*B+b))*(32u*2304u);
            const float* vb = vecs + ((size_t)(i*B+b))*(32u*48u);
            for (int c=0;c<32;c++){
                const float* fc = pb + c*2304;
                const float pf = tw[0]*fc[toff[0]] + tw[1]*fc[toff[1]]
                               + tw[2]*fc[toff[2]] + tw[3]*fc[toff[3]];
                const float* vc = vb + c*48;
                const float vf = vw[0]*vc[voff[0]] + vw[1]*vc[voff[1]];
                accum_feat(krgb, c, pf*vf, sigma, hid, s_wmat);
            }
        }
    }

    // layer-1 activation
    #pragma unroll
    for (int j=0;j<64;j++) hid[j] = gelu_f(hid[j]);

    // view-dir positional encoding (wave-uniform per ray)
    const float inv_n = rsqrtf(dx*dx+dy*dy+dz*dz);
    const float vdx = dx*inv_n, vdy = dy*inv_n, vdz = dz*inv_n;
    float vdpe[27];
    vdpe[0]=vdx; vdpe[1]=vdy; vdpe[2]=vdz;
    #pragma unroll
    for (int fq=0;fq<4;fq++){
        const float fs = (float)(1<<fq);
        vdpe[3+fq*3+0]  = sinf(vdx*fs);
        vdpe[3+fq*3+1]  = sinf(vdy*fs);
        vdpe[3+fq*3+2]  = sinf(vdz*fs);
        vdpe[15+fq*3+0] = cosf(vdx*fs);
        vdpe[15+fq*3+1] = cosf(vdy*fs);
        vdpe[15+fq*3+2] = cosf(vdz*fs);
    }

    // layer 2 (91 -> 64, split into two j-halves to cap register pressure) + layer 3
    float rgb0=s_b2[0], rgb1=s_b2[1], rgb2=s_b2[2];
    #pragma unroll
    for (int half=0; half<2; half++){
        float h2[32];
        #pragma unroll
        for (int j=0;j<32;j++) h2[j] = s_b1[half*32+j];
        #pragma unroll
        for (int k=0;k<64;k++){
            const float v = hid[k];
            const float4* wr = (const float4*)(s_w1 + k*64 + half*32);
            #pragma unroll
            for (int j=0;j<8;j++){
                const float4 w = wr[j];
                h2[4*j+0]+=v*w.x; h2[4*j+1]+=v*w.y; h2[4*j+2]+=v*w.z; h2[4*j+3]+=v*w.w;
            }
        }
        #pragma unroll
        for (int k=0;k<27;k++){
            const float v = vdpe[k];
            const float4* wr = (const float4*)(s_w1 + (64+k)*64 + half*32);
            #pragma unroll
            for (int j=0;j<8;j++){
                const float4 w = wr[j];
                h2[4*j+0]+=v*w.x; h2[4*j+1]+=v*w.y; h2[4*j+2]+=v*w.z; h2[4*j+3]+=v*w.w;
            }
        }
        #pragma unroll
        for (int j=0;j<32;j++){
            const float g = gelu_f(h2[j]);
            const int jj = half*32+j;
            rgb0 += g*s_w2[jj*3+0];
            rgb1 += g*s_w2[jj*3+1];
            rgb2 += g*s_w2[jj*3+2];
        }
    }
    rgb0 = 1.0f/(1.0f+expf(-rgb0));
    rgb1 = 1.0f/(1.0f+expf(-rgb1));
    rgb2 = 1.0f/(1.0f+expf(-rgb2));

    // volume integration: product scan over lanes
    const float sg = fmaxf(sigma, 0.0f);
    const float alpha = active ? (1.0f - expf(-sg*0.03125f)) : 0.0f;
    float v = active ? (1.0f - alpha + 1e-10f) : 1.0f;
    #pragma unroll
    for (int off=1; off<64; off<<=1){
        const float up = __shfl_up(v, off, 64);
        if (lane >= off) v *= up;
    }
    float T = __shfl_up(v, 1, 64);
    if (lane==0) T = 1.0f;
    const float w = active ? alpha*T : 0.0f;

    if (active) out[(size_t)NR*4 + (size_t)ray*NSMP + s] = w;

    float a0=w*rgb0, a1=w*rgb1, a2=w*rgb2, ad=w*mid;
    #pragma unroll
    for (int off=32; off>0; off>>=1){
        a0 += __shfl_down(a0, off, 64);
        a1 += __shfl_down(a1, off, 64);
        a2 += __shfl_down(a2, off, 64);
        ad += __shfl_down(ad, off, 64);
    }
    if (lane==0){
        out[(size_t)ray*3+0]=a0;
        out[(size_t)ray*3+1]=a1;
        out[(size_t)ray*3+2]=a2;
        out[(size_t)NR*3 + (size_t)ray]=ad;
    }
}

__global__ void transpose_mats(const float* __restrict__ in, float* __restrict__ out, int total){
    const int idx = blockIdx.x*blockDim.x+threadIdx.x;
    if (idx < total){
        const int pix = idx % 2304;
        const int c   = (idx / 2304) & 31;
        const int ib  = idx / (2304*32);
        out[((size_t)ib*2304+pix)*32 + c] = in[idx];
    }
}

__global__ void transpose_vecs(const float* __restrict__ in, float* __restrict__ out, int total){
    const int idx = blockIdx.x*blockDim.x+threadIdx.x;
    if (idx < total){
        const int r  = idx % 48;
        const int c  = (idx / 48) & 31;
        const int ib = idx / (48*32);
        out[((size_t)ib*48+r)*32 + c] = in[idx];
    }
}

extern "C" void kernel_launch(void* const* d_in, const int* in_sizes, int n_in,
                              void* d_out, int out_size, void* d_ws, size_t ws_size,
                              hipStream_t stream) {
    const float* rays_o  = (const float*)d_in[0];
    const float* rays_d  = (const float*)d_in[1];
    const float* matrixs = (const float*)d_in[2];
    const float* vectors = (const float*)d_in[3];
    const float* w_mat   = (const float*)d_in[4];
    const float* b_mat   = (const float*)d_in[5];
    const float* w1      = (const float*)d_in[6];
    const float* b1      = (const float*)d_in[7];
    const float* w2      = (const float*)d_in[8];
    const float* b2      = (const float*)d_in[9];
    float* out = (float*)d_out;

    const int B = in_sizes[2] / (3*32*48*48);
    const int R = (in_sizes[0]/3) / B;
    const int NR = B*R;

    const int matsz = 3*B*32*2304;
    const int vecsz = 3*B*32*48;
    const size_t need = ((size_t)matsz + (size_t)vecsz)*sizeof(float);

    const int nblk = (NR + 3)/4;
    if (ws_size >= need){
        float* tm = (float*)d_ws;
        float* tv = tm + matsz;
        transpose_mats<<<(matsz+255)/256, 256, 0, stream>>>(matrixs, tm, matsz);
        transpose_vecs<<<(vecsz+255)/256, 256, 0, stream>>>(vectors, tv, vecsz);
        render_kernel<true><<<nblk, 256, 0, stream>>>(rays_o, rays_d, tm, tv,
            w_mat, b_mat, w1, b1, w2, b2, out, B, R);
    } else {
        render_kernel<false><<<nblk, 256, 0, stream>>>(rays_o, rays_d, matrixs, vectors,
            w_mat, b_mat, w1, b1, w2, b2, out, B, R);
    }
}